// Round 11
// baseline (278.796 us; speedup 1.0000x reference)
//
#include <hip/hip_runtime.h>
#include <hip/hip_bf16.h>
#include <float.h>
#include <stdint.h>

#define NPT    4096
#define EMB    512
#define NH     8
#define HD     64
#define KSPLIT 32     // score k-range split: KRANGE = 128 (4 tiles of 32)

typedef __attribute__((ext_vector_type(8))) short bf16x8;
typedef __attribute__((ext_vector_type(4))) float f32x4;
typedef uint32_t u32;

// async global->LDS DMA, 16B/lane. LDS dest = wave-uniform base + lane*16.
__device__ __forceinline__ void async_ld16(const void* gsrc, void* ldst) {
    __builtin_amdgcn_global_load_lds(
        (const __attribute__((address_space(1))) u32*)gsrc,
        (__attribute__((address_space(3))) u32*)ldst, 16, 0, 0);
}

// exact 3-way bf16 split of f32 (hi+mid+lo covers all 24 mantissa bits)
__device__ __forceinline__ void split3(float a, unsigned short& h,
                                       unsigned short& m, unsigned short& l) {
    __hip_bfloat16 bh = __float2bfloat16(a);
    float fh = __bfloat162float(bh);
    float r1 = a - fh;
    __hip_bfloat16 bm = __float2bfloat16(r1);
    float fm = __bfloat162float(bm);
    float r2 = r1 - fm;
    __hip_bfloat16 bl = __float2bfloat16(r2);
    h = *reinterpret_cast<unsigned short*>(&bh);
    m = *reinterpret_cast<unsigned short*>(&bm);
    l = *reinterpret_cast<unsigned short*>(&bl);
}

// ---------------------------------------------------------------------------
// 1) fused prep: y=0 split x (granule-major); y=1..3 split W (granule-major);
//    y=4 pack adj into TRANSPOSED bitmask bits_t[kword(128)][q(4096)]
//    xs granule: [p][tn16(256)][kc(16)][kg(4)][i16][8]  (1 KB-coalescible frags)
// ---------------------------------------------------------------------------
__global__ __launch_bounds__(256) void prep_kernel(const float* __restrict__ x,
                                                   const float* __restrict__ wq,
                                                   const float* __restrict__ wk,
                                                   const float* __restrict__ wv,
                                                   const int* __restrict__ adj,
                                                   unsigned short* __restrict__ xs,
                                                   unsigned short* __restrict__ wqs,
                                                   unsigned short* __restrict__ wks,
                                                   unsigned short* __restrict__ wvs,
                                                   unsigned* __restrict__ bits_t) {
    int y = blockIdx.y;
    size_t i = (size_t)blockIdx.x * 256 + threadIdx.x;
    if (y == 4) {                               // pack adj (reads coalesced)
        int q = (int)(i >> 7), w = (int)i & 127;
        const int4* p = (const int4*)(adj + (size_t)q * NPT + w * 32);
        unsigned m = 0;
#pragma unroll
        for (int j = 0; j < 8; ++j) {
            int4 v = p[j];
            m |= (v.x != 0 ? 1u : 0u) << (j * 4 + 0);
            m |= (v.y != 0 ? 1u : 0u) << (j * 4 + 1);
            m |= (v.z != 0 ? 1u : 0u) << (j * 4 + 2);
            m |= (v.w != 0 ? 1u : 0u) << (j * 4 + 3);
        }
        bits_t[(size_t)w * NPT + q] = m;        // transposed write
    } else if (y == 0) {
        const size_t PL = (size_t)NPT * EMB;
        float4 v = ((const float4*)x)[i];
        int n  = (int)(i >> 7);
        int k0 = ((int)i & 127) * 4;
        int kc = k0 >> 5, kg = (k0 >> 3) & 3, dd = k0 & 7;
        size_t off = ((((size_t)(n >> 4) * 16 + kc) * 4 + kg) * 16 + (n & 15)) * 8 + dd;
        ushort4 h, m, l;
        split3(v.x, h.x, m.x, l.x);
        split3(v.y, h.y, m.y, l.y);
        split3(v.z, h.z, m.z, l.z);
        split3(v.w, h.w, m.w, l.w);
        *(ushort4*)(xs + off)          = h;
        *(ushort4*)(xs + PL + off)     = m;
        *(ushort4*)(xs + 2 * PL + off) = l;
    } else {
        const size_t WPL = 262144;
        if (i >= WPL / 4) return;
        const float* src = (y == 1) ? wq : (y == 2) ? wk : wv;
        unsigned short* dst = (y == 1) ? wqs : (y == 2) ? wks : wvs;
        float4 v = ((const float4*)src)[i];
        int e  = (int)(i >> 7);
        int k0 = ((int)i & 127) * 4;
        int ebk = e >> 6, el = e & 63;
        int kc = k0 >> 5, g = (k0 >> 3) & 3, dd = k0 & 7;
        size_t off = ((((size_t)ebk * 16 + kc) * 4 + g) * 64 + el) * 8 + dd;
        ushort4 h, m, l;
        split3(v.x, h.x, m.x, l.x);
        split3(v.y, h.y, m.y, l.y);
        split3(v.z, h.z, m.z, l.z);
        split3(v.w, h.w, m.w, l.w);
        *(ushort4*)(dst + off)           = h;
        *(ushort4*)(dst + WPL + off)     = m;
        *(ushort4*)(dst + 2 * WPL + off) = l;
    }
}

// ---------------------------------------------------------------------------
// 2) z-MERGED projection GEMM: block (tn, ebk) computes Q, K, AND V for its
//    128-n tile and head. W tile [3z][3p][4kg][64e][8] = 36 KB, single-buffer
//    LDS via global_load_lds. Waves split 2n x 2e (nt=4, mt=2). x-fragments
//    are 1 KB-coalesced global loads from granule-major xs (reused 3x by z).
//    x bytes: 288 MB (R10) -> 96 MB; x-frag txns 16 half-lines -> 8 full.
// ---------------------------------------------------------------------------
__global__ __launch_bounds__(256) void gemm_mfma(const unsigned short* __restrict__ xs,
                                                 const unsigned short* __restrict__ wqs,
                                                 const unsigned short* __restrict__ wks,
                                                 const unsigned short* __restrict__ wvs,
                                                 unsigned short* __restrict__ Q3,
                                                 unsigned short* __restrict__ K3,
                                                 float* __restrict__ V) {
    const size_t XPL = (size_t)NPT * EMB;
    const size_t WPL = 262144;
    const size_t OPL = (size_t)NH * NPT * HD;

    const int tn  = blockIdx.x;            // n-tile (128 rows)
    const int ebk = blockIdx.y;            // head
    const int tid = threadIdx.x;
    const int wv = tid >> 6, lane = tid & 63;
    const int wn = wv & 1, we = wv >> 1;   // 2n x 2e wave grid
    const int m = lane & 15, quad = lane >> 4;
    const int n0 = tn * 128 + wn * 64;     // wave's n base (nt*16+m spans 64)
    const int e0 = we * 32;                // wave's head-local e base (mt*16+quad*4)

    // [z][p][kg][e64][8] shorts = 36 KB
    __shared__ __align__(16) unsigned short Ws[3 * 3 * 4 * 64 * 8];

    const unsigned short* Wz[3] = {wqs, wks, wvs};

    f32x4 acc[3][2][4];                    // [z][mt][nt]
#pragma unroll
    for (int z = 0; z < 3; ++z)
#pragma unroll
        for (int mt = 0; mt < 2; ++mt)
#pragma unroll
            for (int nt = 0; nt < 4; ++nt) acc[z][mt][nt] = (f32x4){0.f, 0.f, 0.f, 0.f};

#pragma unroll 1
    for (int kc = 0; kc < 16; ++kc) {
        __syncthreads();                   // all waves done reading Ws (prev kc)
        // stage W tile: 36 chunks of 1 KB, 9 per wave
#pragma unroll
        for (int i2 = 0; i2 < 9; ++i2) {
            int c = wv + 4 * i2;           // 0..35
            int z = c / 12, p = (c / 4) % 3, kg = c & 3;
            const unsigned short* src = Wz[z] + (size_t)p * WPL
                + (((size_t)ebk * 16 + kc) * 4 + kg) * 512 + lane * 8;
            async_ld16(src, &Ws[((z * 3 + p) * 4 + kg) * 512]);
        }
        // x fragments for this kc (coalesced 1 KB each), reused by all 3 z
        bf16x8 xf[4][3];
#pragma unroll
        for (int nt = 0; nt < 4; ++nt) {
            int tni = tn * 8 + wn * 4 + nt;    // n>>4 granule index
#pragma unroll
            for (int p = 0; p < 3; ++p)
                xf[nt][p] = *(const bf16x8*)(xs + (size_t)p * XPL
                    + ((((size_t)tni * 16 + kc) * 4 + quad) * 16 + m) * 8);
        }
        __syncthreads();                   // drains DMA (and xf, needed anyway)

        // products (A-plane ga, B-plane pb): ga=0: pb 0,1,2; ga=1: 0,1; ga=2: 0
#pragma unroll
        for (int ga = 0; ga < 3; ++ga) {
#pragma unroll
            for (int z = 0; z < 3; ++z) {
                bf16x8 af[2];
#pragma unroll
                for (int mt = 0; mt < 2; ++mt)
                    af[mt] = *(const bf16x8*)
                        &Ws[(((z * 3 + ga) * 4 + quad) * 64 + e0 + mt * 16 + m) * 8];
#pragma unroll
                for (int pb = 0; pb < 3 - ga; ++pb)
#pragma unroll
                    for (int mt = 0; mt < 2; ++mt)
#pragma unroll
                        for (int nt = 0; nt < 4; ++nt)
                            acc[z][mt][nt] = __builtin_amdgcn_mfma_f32_16x16x32_bf16(
                                af[mt], xf[nt][pb], acc[z][mt][nt], 0, 0, 0);
            }
        }
    }

    // epilogue. C: col(lane&15)=n, row(quad*4+r)=e
    const int h = ebk;
#pragma unroll
    for (int z = 0; z < 3; ++z)
#pragma unroll
        for (int mt = 0; mt < 2; ++mt)
#pragma unroll
            for (int nt = 0; nt < 4; ++nt) {
                const int n = n0 + nt * 16 + m;
                const int dL = e0 + mt * 16 + quad * 4;   // head-local d
                f32x4 a = acc[z][mt][nt];
                if (z == 2) {
                    *(f32x4*)(V + (size_t)n * EMB + ebk * 64 + dL) = a;
                } else {
                    ushort4 ph, pm, pl;
                    split3(a[0], ph.x, pm.x, pl.x);
                    split3(a[1], ph.y, pm.y, pl.y);
                    split3(a[2], ph.z, pm.z, pl.z);
                    split3(a[3], ph.w, pm.w, pl.w);
                    unsigned short* O3 = (z == 0) ? Q3 : K3;
                    size_t off = ((size_t)h * 128 + (n >> 5)) * 2048
                               + (dL >> 3) * 256 + (n & 31) * 8 + (dL & 7);
                    *(ushort4*)(O3 + off)           = ph;
                    *(ushort4*)(O3 + OPL + off)     = pm;
                    *(ushort4*)(O3 + 2 * OPL + off) = pl;
                }
            }
}

// ---------------------------------------------------------------------------
// 3) masked argmax via bf16x3 MFMA, 16x16x32. Triple-buffered K tiles via
//    global_load_lds with MANUAL s_waitcnt vmcnt(3)+s_barrier (R10 win —
//    unchanged). Q3 granule-major -> coalesced qf; bits_t transposed.
// ---------------------------------------------------------------------------
__global__ __launch_bounds__(256) void score_mfma(const unsigned short* __restrict__ Q3,
                                                  const unsigned short* __restrict__ K3,
                                                  const unsigned* __restrict__ bits_t,
                                                  float* __restrict__ pval,
                                                  int* __restrict__ pidx) {
    const int qb = blockIdx.x * 128;
    const int ks = blockIdx.y;
    const int tid = threadIdx.x;
    const int wv = tid >> 6, lane = tid & 63;
    const int m = lane & 15, quad = lane >> 4;
    const size_t PL = (size_t)NH * NPT * HD;
    const int kq = qb + wv * 32;

    __shared__ __align__(16) unsigned short Ks[3][3 * 2048];   // 3 x 12 KB

    auto prefetchK = [&](int t) {          // 3 DMA chunks per wave per tile
        int h = t >> 2, kt = ks * 4 + (t & 3), buf = t % 3;
#pragma unroll
        for (int i2 = 0; i2 < 3; ++i2) {
            int c = wv + 4 * i2;
            int p = c >> 2, sub = c & 3;
            const unsigned short* src = K3 + (size_t)p * PL
                + ((size_t)h * 128 + kt) * 2048 + (sub * 64 + lane) * 8;
            async_ld16(src, &Ks[buf][p * 2048 + sub * 512]);
        }
    };

    prefetchK(0);
    prefetchK(1);

    bf16x8 qf[2][2][3];
    float bestv[2]; int besti[2];

#pragma unroll 1
    for (int t = 0; t < NH * 4; ++t) {
        const int h = t >> 2, kst = t & 3, buf = t % 3;
        const int kbase = ks * 128 + kst * 32;

        // wait own 3 chunks of tile t (issued at t-2); tile t+1's stay in flight
        asm volatile("s_waitcnt vmcnt(3)\n\ts_barrier" ::: "memory");

        if (kst == 0) {                    // coalesced qf from granule-major Q3
#pragma unroll
            for (int nt = 0; nt < 2; ++nt)
#pragma unroll
                for (int dc = 0; dc < 2; ++dc)
#pragma unroll
                    for (int p = 0; p < 3; ++p)
                        qf[nt][dc][p] = *(const bf16x8*)(Q3 + (size_t)p * PL
                            + ((size_t)h * 128 + (kq >> 5)) * 2048
                            + (dc * 4 + quad) * 256 + (nt * 16 + m) * 8);
            bestv[0] = bestv[1] = -FLT_MAX;
            besti[0] = besti[1] = 0;
        }

        unsigned bw[2];                    // coalesced: lanes -> consecutive q
#pragma unroll
        for (int nt = 0; nt < 2; ++nt)
            bw[nt] = bits_t[(size_t)(ks * 4 + kst) * NPT + kq + nt * 16 + m];

        if (t + 2 < NH * 4) prefetchK(t + 2);

        f32x4 acc[2][2];
#pragma unroll
        for (int mt = 0; mt < 2; ++mt)
#pragma unroll
            for (int nt = 0; nt < 2; ++nt) acc[mt][nt] = (f32x4){0.f, 0.f, 0.f, 0.f};

#pragma unroll
        for (int ga = 0; ga < 3; ++ga) {
            bf16x8 kf[2][2];
#pragma unroll
            for (int mt = 0; mt < 2; ++mt)
#pragma unroll
                for (int dc = 0; dc < 2; ++dc)
                    kf[mt][dc] = *(const bf16x8*)
                        &Ks[buf][ga * 2048 + ((dc * 4 + quad) * 32 + mt * 16 + m) * 8];
#pragma unroll
            for (int pb = 0; pb < 3 - ga; ++pb)
#pragma unroll
                for (int dc = 0; dc < 2; ++dc)
#pragma unroll
                    for (int mt = 0; mt < 2; ++mt)
#pragma unroll
                        for (int nt = 0; nt < 2; ++nt)
                            acc[mt][nt] = __builtin_amdgcn_mfma_f32_16x16x32_bf16(
                                kf[mt][dc], qf[nt][dc][pb], acc[mt][nt], 0, 0, 0);
        }

        // C: col=lane&15 -> q; row=quad*4+r -> k
#pragma unroll
        for (int nt = 0; nt < 2; ++nt) {
            unsigned w = bw[nt];
#pragma unroll
            for (int mt = 0; mt < 2; ++mt) {
                int k0 = mt * 16 + quad * 4;
                f32x4 a = acc[mt][nt];
#pragma unroll
                for (int r = 0; r < 4; ++r) {
                    if ((w >> (k0 + r)) & 1u) {
                        float s = a[r];
                        if (s > bestv[nt]) { bestv[nt] = s; besti[nt] = kbase + k0 + r; }
                    }
                }
            }
        }

        if (kst == 3) {                    // end of head: reduce over quad groups
#pragma unroll
            for (int nt = 0; nt < 2; ++nt) {
                float v = bestv[nt]; int bi = besti[nt];
#pragma unroll
                for (int off = 16; off < 64; off <<= 1) {
                    float ov = __shfl_xor(v, off);
                    int   oi = __shfl_xor(bi, off);
                    if (ov > v || (ov == v && oi < bi)) { v = ov; bi = oi; }
                }
                if (quad == 0) {
                    size_t o = ((size_t)h * KSPLIT + ks) * NPT + kq + nt * 16 + m;
                    pval[o] = v; pidx[o] = bi;
                }
            }
        }
    }
}

// ---------------------------------------------------------------------------
// 4) reduce k-split partials, gather winner V row * (1/NH)
// ---------------------------------------------------------------------------
__global__ __launch_bounds__(128) void gather_out(const float* __restrict__ V,
                                                  const float* __restrict__ pval,
                                                  const int* __restrict__ pidx,
                                                  float* __restrict__ out) {
    const int q = blockIdx.x;
    const int tid = threadIdx.x;
    __shared__ int widx[NH];
    if (tid < NH) {
        float bv = -FLT_MAX; int bi = 0;
        for (int ks = 0; ks < KSPLIT; ++ks) {
            size_t off = ((size_t)tid * KSPLIT + ks) * NPT + q;
            float v = pval[off];
            if (v > bv) { bv = v; bi = pidx[off]; }
        }
        widx[tid] = bi;
    }
    __syncthreads();
    const int h = tid >> 4;
    const int d4 = (tid & 15) * 4;
    const int k = widx[h];
    float4 v = *(const float4*)(V + (size_t)k * EMB + h * HD + d4);
    v.x *= 0.125f; v.y *= 0.125f; v.z *= 0.125f; v.w *= 0.125f;
    *(float4*)(out + (size_t)q * EMB + h * HD + d4) = v;
}

// ---------------------------------------------------------------------------
extern "C" void kernel_launch(void* const* d_in, const int* in_sizes, int n_in,
                              void* d_out, int out_size, void* d_ws, size_t ws_size,
                              hipStream_t stream) {
    const float* x   = (const float*)d_in[0];
    const int*   adj = (const int*)d_in[1];
    const float* WQ  = (const float*)d_in[2];
    const float* WK  = (const float*)d_in[3];
    const float* WV  = (const float*)d_in[4];
    // we/be are dead: energy is constant along k -> argmax unchanged.
    float* out = (float*)d_out;

    char* ws = (char*)d_ws;
    const size_t HMB = 512u * 1024;
    unsigned short* xs   = (unsigned short*)(ws);                 // 12 MB (dead after gemm)
    unsigned short* wqs  = (unsigned short*)(ws + 24 * HMB);
    unsigned short* wks  = (unsigned short*)(ws + 27 * HMB);
    unsigned short* wvs  = (unsigned short*)(ws + 30 * HMB);
    unsigned short* Q3   = (unsigned short*)(ws + 33 * HMB);      // 12 MB granule-major
    unsigned short* K3   = (unsigned short*)(ws + 57 * HMB);      // 12 MB granule-major
    float*          V    = (float*)(ws + 81 * HMB);               // 8 MB
    unsigned*       bits = (unsigned*)(ws + 97 * HMB);            // 2 MB transposed
    float*          pval = (float*)(ws);                          // 4 MB, aliases dead xs
    int*            pidx = (int*)(ws + 8 * HMB);                  // 4 MB, aliases dead xs

    prep_kernel<<<dim3(2048, 5), dim3(256), 0, stream>>>(x, WQ, WK, WV, adj,
                                                         xs, wqs, wks, wvs, bits);
    gemm_mfma<<<dim3(32, NH), dim3(256), 0, stream>>>(xs, wqs, wks, wvs, Q3, K3, V);
    score_mfma<<<dim3(NPT / 128, KSPLIT), dim3(256), 0, stream>>>(Q3, K3, bits, pval, pidx);
    gather_out<<<dim3(NPT), dim3(128), 0, stream>>>(V, pval, pidx, out);
}